// Round 8
// baseline (396.923 us; speedup 1.0000x reference)
//
#include <hip/hip_runtime.h>
#include <hip/hip_bf16.h>

// ---------------------------------------------------------------------------
// TwoLayerGCN. Round 8:
//  - REVERT spmm to R6 unroll x4 (R7's 8-deep pipeline: 57->59.7us, VGPR
//    20->44, occ 65->41% - gather sits on random-access fetch ceiling
//    ~3.6 TB/s; deeper MLP only costs registers)
//  - h2 stored bf16: gemm<256> BF16OUT, pool_head reads bf16 (2 rows/iter,
//    float2 acc, LDS merge). -25MB write, -13MB fetch.
// ---------------------------------------------------------------------------

typedef short v8s __attribute__((ext_vector_type(8)));
typedef float v4f __attribute__((ext_vector_type(4)));

__device__ inline unsigned bf16u(float f) {           // fp32 -> bf16 bits (RNE)
    unsigned u = __builtin_bit_cast(unsigned, f);
    return (u + 0x7fffu + ((u >> 16) & 1u)) >> 16;
}
__device__ inline float bflo(unsigned v) { return __builtin_bit_cast(float, v << 16); }
__device__ inline float bfhi(unsigned v) { return __builtin_bit_cast(float, v & 0xffff0000u); }
__device__ inline float f32bits(unsigned v) { return __builtin_bit_cast(float, v); }

// ------------------- fused prep: x->bf16, degree hist, W^T -------------------
// blocks [0,6250): xh[i] = bf16(x[i]) (float4 granularity, 1.6M elems)
// blocks [6250,9375): deg histogram over edge dst
// blocks [9375,9631): Wt1[n*128+k] = bf16(W1[k*256+n]) (threads<128)
// blocks [9631,9887): Wt2[n*256+k] = bf16(W2[k*256+n])
__global__ __launch_bounds__(256) void prep(
    const float* __restrict__ x, ushort* __restrict__ xh,
    const int* __restrict__ dst, int* __restrict__ deg,
    const float* __restrict__ W1, ushort* __restrict__ Wt1,
    const float* __restrict__ W2, ushort* __restrict__ Wt2, int E)
{
    int b = blockIdx.x;
    int t = threadIdx.x;
    if (b < 6250) {
        int i = b * 256 + t;                 // n4 = 1600000
        if (i < 1600000) {
            float4 v = ((const float4*)x)[i];
            unsigned lo = (bf16u(v.y) << 16) | bf16u(v.x);
            unsigned hi = (bf16u(v.w) << 16) | bf16u(v.z);
            ((uint2*)xh)[i] = make_uint2(lo, hi);
        }
    } else if (b < 9375) {
        int e = (b - 6250) * 256 + t;
        if (e < E) atomicAdd(&deg[dst[e]], 1);
    } else if (b < 9631) {
        int n = b - 9375;
        if (t < 128) Wt1[n * 128 + t] = (ushort)bf16u(W1[t * 256 + n]);
    } else {
        int n = b - 9631;
        Wt2[n * 256 + t] = (ushort)bf16u(W2[t * 256 + n]);
    }
}

// ---------------- CSR-by-destination build (once per launch) ----------------

__global__ __launch_bounds__(256) void scan_block(
    const int* __restrict__ deg, int* __restrict__ off,
    int* __restrict__ blocksums, int n)
{
    __shared__ int s[256];
    int tid = threadIdx.x;
    int gid = blockIdx.x * 256 + tid;
    int v = (gid < n) ? deg[gid] : 0;
    s[tid] = v;
    __syncthreads();
    for (int o = 1; o < 256; o <<= 1) {
        int t = (tid >= o) ? s[tid - o] : 0;
        __syncthreads();
        s[tid] += t;
        __syncthreads();
    }
    if (gid < n) off[gid] = s[tid] - v;
    if (tid == 255) blocksums[blockIdx.x] = s[255];
}

// fused: every block redundantly scans the <=256 block sums in LDS, then
// applies its own exclusive block offset.
__global__ __launch_bounds__(256) void scan_apply(
    int* __restrict__ off, const int* __restrict__ blocksums,
    int* __restrict__ cursor, int n, int E, int nb)
{
    __shared__ int s[256];
    int tid = threadIdx.x;
    int v = (tid < nb) ? blocksums[tid] : 0;
    s[tid] = v;
    __syncthreads();
    for (int o = 1; o < 256; o <<= 1) {
        int t = (tid >= o) ? s[tid - o] : 0;
        __syncthreads();
        s[tid] += t;
        __syncthreads();
    }
    int b = blockIdx.x;
    int boff = (b == 0) ? 0 : s[b - 1];
    int gid = b * 256 + tid;
    if (gid < n) {
        int w = off[gid] + boff;
        off[gid] = w;
        cursor[gid] = w;
    }
    if (gid == 0) off[n] = E;
}

__global__ __launch_bounds__(256) void csr_fill(
    const int* __restrict__ src, const int* __restrict__ dst,
    const float* __restrict__ w, int* __restrict__ cursor,
    uint2* __restrict__ edges, int E)
{
    int e = blockIdx.x * 256 + threadIdx.x;
    if (e >= E) return;
    int d = dst[e];
    int p = atomicAdd(&cursor[d], 1);
    edges[p] = make_uint2((unsigned)src[e],
                          __builtin_bit_cast(unsigned, w[e]));
}

// ----------------------- gather SpMM (bf16 in/out) --------------------------
// 128 feats: lane owns feats {2l, 2l+1}; unroll x4 (4 row loads in flight).
__global__ __launch_bounds__(256) void spmm128(
    const ushort* __restrict__ xh, const int* __restrict__ off,
    const uint2* __restrict__ edges, ushort* __restrict__ S, int n)
{
    int node = blockIdx.x * 4 + (threadIdx.x >> 6);
    if (node >= n) return;
    int lane = threadIdx.x & 63;
    const unsigned* base = (const unsigned*)xh;   // row stride 64 uints
    int e0 = off[node], e1 = off[node + 1];
    float a0 = 0.f, a1 = 0.f;
    int e = e0;
    for (; e + 4 <= e1; e += 4) {
        uint2 ed0 = edges[e],     ed1 = edges[e + 1];
        uint2 ed2 = edges[e + 2], ed3 = edges[e + 3];
        float w0 = f32bits(ed0.y), w1 = f32bits(ed1.y);
        float w2 = f32bits(ed2.y), w3 = f32bits(ed3.y);
        unsigned v0 = base[(size_t)ed0.x * 64 + lane];
        unsigned v1 = base[(size_t)ed1.x * 64 + lane];
        unsigned v2 = base[(size_t)ed2.x * 64 + lane];
        unsigned v3 = base[(size_t)ed3.x * 64 + lane];
        a0 += bflo(v0) * w0 + bflo(v1) * w1 + bflo(v2) * w2 + bflo(v3) * w3;
        a1 += bfhi(v0) * w0 + bfhi(v1) * w1 + bfhi(v2) * w2 + bfhi(v3) * w3;
    }
    for (; e < e1; e++) {
        uint2 ed = edges[e];
        float w0 = f32bits(ed.y);
        unsigned v0 = base[(size_t)ed.x * 64 + lane];
        a0 += bflo(v0) * w0;
        a1 += bfhi(v0) * w0;
    }
    ((unsigned*)S)[(size_t)node * 64 + lane] = (bf16u(a1) << 16) | bf16u(a0);
}

// 256 feats: lane owns feats {4l..4l+3}; unroll x4.
__global__ __launch_bounds__(256) void spmm256(
    const ushort* __restrict__ hh, const int* __restrict__ off,
    const uint2* __restrict__ edges, ushort* __restrict__ S, int n)
{
    int node = blockIdx.x * 4 + (threadIdx.x >> 6);
    if (node >= n) return;
    int lane = threadIdx.x & 63;
    const uint2* base = (const uint2*)hh;          // row stride 64 uint2
    int e0 = off[node], e1 = off[node + 1];
    float a0 = 0.f, a1 = 0.f, a2 = 0.f, a3 = 0.f;
    int e = e0;
    for (; e + 4 <= e1; e += 4) {
        uint2 ed0 = edges[e],     ed1 = edges[e + 1];
        uint2 ed2 = edges[e + 2], ed3 = edges[e + 3];
        float w0 = f32bits(ed0.y), w1 = f32bits(ed1.y);
        float w2 = f32bits(ed2.y), w3 = f32bits(ed3.y);
        uint2 v0 = base[(size_t)ed0.x * 64 + lane];
        uint2 v1 = base[(size_t)ed1.x * 64 + lane];
        uint2 v2 = base[(size_t)ed2.x * 64 + lane];
        uint2 v3 = base[(size_t)ed3.x * 64 + lane];
        a0 += bflo(v0.x) * w0 + bflo(v1.x) * w1 + bflo(v2.x) * w2 + bflo(v3.x) * w3;
        a1 += bfhi(v0.x) * w0 + bfhi(v1.x) * w1 + bfhi(v2.x) * w2 + bfhi(v3.x) * w3;
        a2 += bflo(v0.y) * w0 + bflo(v1.y) * w1 + bflo(v2.y) * w2 + bflo(v3.y) * w3;
        a3 += bfhi(v0.y) * w0 + bfhi(v1.y) * w1 + bfhi(v2.y) * w2 + bfhi(v3.y) * w3;
    }
    for (; e < e1; e++) {
        uint2 ed = edges[e];
        float w0 = f32bits(ed.y);
        uint2 v0 = base[(size_t)ed.x * 64 + lane];
        a0 += bflo(v0.x) * w0;
        a1 += bfhi(v0.x) * w0;
        a2 += bflo(v0.y) * w0;
        a3 += bfhi(v0.y) * w0;
    }
    uint2 o;
    o.x = (bf16u(a1) << 16) | bf16u(a0);
    o.y = (bf16u(a3) << 16) | bf16u(a2);
    ((uint2*)S)[(size_t)node * 64 + lane] = o;
}

// ----------------------- LDS-tiled MFMA bf16 GEMM ---------------------------
template <int K, bool BF16OUT>
__global__ __launch_bounds__(256) void gemm_tile(
    const ushort* __restrict__ A, const ushort* __restrict__ Wt,
    const float* __restrict__ bias, void* __restrict__ out, int M)
{
    __shared__ __align__(16) ushort As[128 * 32];
    __shared__ __align__(16) ushort Bs[128 * 32];

    const int tid = threadIdx.x;
    const int bm = blockIdx.x * 128;
    const int bn = blockIdx.y * 128;
    const int wave = tid >> 6, lane = tid & 63;
    const int wm = wave >> 1, wn = wave & 1;
    const int r = lane & 15, q = lane >> 4;

    const int o0 = tid * 16;
    const int row0 = o0 >> 6;
    const int kb0 = o0 & 63;

    const char* Ab = (const char*)A;
    const char* Bb = (const char*)Wt;

    uint4 ra0, ra1, rb0, rb1;
    ra0 = *(const uint4*)(Ab + ((size_t)(bm + row0)      * K) * 2 + kb0);
    ra1 = *(const uint4*)(Ab + ((size_t)(bm + row0 + 64) * K) * 2 + kb0);
    rb0 = *(const uint4*)(Bb + ((size_t)(bn + row0)      * K) * 2 + kb0);
    rb1 = *(const uint4*)(Bb + ((size_t)(bn + row0 + 64) * K) * 2 + kb0);

    v4f acc[4][4];
    #pragma unroll
    for (int i = 0; i < 4; i++)
        #pragma unroll
        for (int j = 0; j < 4; j++) acc[i][j] = (v4f){0.f, 0.f, 0.f, 0.f};

    const int NK = K / 32;
    for (int ks = 0; ks < NK; ks++) {
        __syncthreads();
        *(uint4*)((char*)As + o0)        = ra0;
        *(uint4*)((char*)As + o0 + 4096) = ra1;
        *(uint4*)((char*)Bs + o0)        = rb0;
        *(uint4*)((char*)Bs + o0 + 4096) = rb1;
        if (ks + 1 < NK) {
            const int kof = (ks + 1) * 64;
            ra0 = *(const uint4*)(Ab + ((size_t)(bm + row0)      * K) * 2 + kof + kb0);
            ra1 = *(const uint4*)(Ab + ((size_t)(bm + row0 + 64) * K) * 2 + kof + kb0);
            rb0 = *(const uint4*)(Bb + ((size_t)(bn + row0)      * K) * 2 + kof + kb0);
            rb1 = *(const uint4*)(Bb + ((size_t)(bn + row0 + 64) * K) * 2 + kof + kb0);
        }
        __syncthreads();

        v8s af[4], bf[4];
        #pragma unroll
        for (int i = 0; i < 4; i++)
            af[i] = *(const v8s*)(As + (wm * 64 + i * 16 + r) * 32 + q * 8);
        #pragma unroll
        for (int j = 0; j < 4; j++)
            bf[j] = *(const v8s*)(Bs + (wn * 64 + j * 16 + r) * 32 + q * 8);
        #pragma unroll
        for (int i = 0; i < 4; i++)
            #pragma unroll
            for (int j = 0; j < 4; j++)
                acc[i][j] = __builtin_amdgcn_mfma_f32_16x16x32_bf16(
                    af[i], bf[j], acc[i][j], 0, 0, 0);
    }

    #pragma unroll
    for (int j = 0; j < 4; j++) {
        int col = bn + wn * 64 + j * 16 + r;
        float b = bias[col];
        #pragma unroll
        for (int i = 0; i < 4; i++) {
            #pragma unroll
            for (int ii = 0; ii < 4; ii++) {
                int row = bm + wm * 64 + i * 16 + q * 4 + ii;
                if (row < M) {
                    float v = fmaxf(acc[i][j][ii] + b, 0.f);
                    if constexpr (BF16OUT)
                        ((ushort*)out)[(size_t)row * 256 + col] = (ushort)bf16u(v);
                    else
                        ((float*)out)[(size_t)row * 256 + col] = v;
                }
            }
        }
    }
}

// --------------------- fused pool + dense head + output ---------------------
// h2 is bf16 [N,256]. seg_ids sorted: graph gi owns a contiguous node range.
// Pool phase: 256 threads cover 2 rows x 128 feature-pairs per iteration
// (uint loads, float2 accum), LDS merge of the two row-groups; then dense
// head g2=relu(g@Wd+bd), out[gi]=g2@Wo+bo in the same block.
__global__ __launch_bounds__(256) void pool_head(
    const ushort* __restrict__ h2, const int* __restrict__ seg,
    const float* __restrict__ Wd, const float* __restrict__ bd,
    const float* __restrict__ Wo, const float* __restrict__ bo,
    float* __restrict__ out, int n)
{
    int gi = blockIdx.x;
    int tid = threadIdx.x;
    int f2 = tid & 127;          // feature pair {2*f2, 2*f2+1}
    int rh = tid >> 7;           // row-group 0/1

    int lo = 0, hi = n;
    while (lo < hi) { int m = (lo + hi) >> 1; if (seg[m] < gi) lo = m + 1; else hi = m; }
    int start = lo;
    hi = n;
    while (lo < hi) { int m = (lo + hi) >> 1; if (seg[m] < gi + 1) lo = m + 1; else hi = m; }
    int end = lo;

    const unsigned* h2u = (const unsigned*)h2;   // row stride 128 uints
    float ax = 0.f, ay = 0.f;
    for (int nn = start + rh; nn < end; nn += 2) {
        unsigned u = h2u[(size_t)nn * 128 + f2];
        ax += bflo(u);
        ay += bfhi(u);
    }

    __shared__ float2 s2[256];
    s2[tid] = make_float2(ax, ay);
    __syncthreads();

    __shared__ float gr[256];
    if (tid < 128) {
        float2 a = s2[tid], b = s2[tid + 128];
        gr[2 * tid]     = a.x + b.x;
        gr[2 * tid + 1] = a.y + b.y;
    }
    __syncthreads();

    int j = tid;
    float a2 = bd[j];
    for (int k = 0; k < 256; k++)
        a2 += gr[k] * Wd[(size_t)k * 256 + j];
    a2 = fmaxf(a2, 0.f);

    float v = a2 * Wo[j];
    #pragma unroll
    for (int off = 32; off > 0; off >>= 1)
        v += __shfl_down(v, off, 64);
    __shared__ float partial[4];
    if ((j & 63) == 0) partial[j >> 6] = v;
    __syncthreads();
    if (j == 0)
        out[gi] = partial[0] + partial[1] + partial[2] + partial[3] + bo[0];
}

extern "C" void kernel_launch(void* const* d_in, const int* in_sizes, int n_in,
                              void* d_out, int out_size, void* d_ws, size_t ws_size,
                              hipStream_t stream) {
    const float* x   = (const float*)d_in[0];
    const int*   esrc= (const int*)  d_in[1];
    const int*   edst= (const int*)  d_in[2];
    const float* ew  = (const float*)d_in[3];
    const int*   seg = (const int*)  d_in[4];
    const float* W1  = (const float*)d_in[5];
    const float* b1  = (const float*)d_in[6];
    const float* W2  = (const float*)d_in[7];
    const float* b2  = (const float*)d_in[8];
    const float* Wd  = (const float*)d_in[9];
    const float* bd  = (const float*)d_in[10];
    const float* Wo  = (const float*)d_in[11];
    const float* bo  = (const float*)d_in[12];
    float* out = (float*)d_out;

    const int N = 50000, E = 800000, G = 128, H = 256, F = 128;
    const int NPAD = 50048;            // 391 * 128
    const int NB = (N + 255) / 256;    // 196

    // workspace; region0 reused: {xh, S1} early, h2 (bf16) late
    char* p = (char*)d_ws;
    char* region0 = p;                  p += (size_t)N * H * sizeof(float);    // 51.2 MB
    ushort* xh = (ushort*)region0;                                             // [N,128] bf16
    ushort* S1 = (ushort*)(region0 + (size_t)N * F * sizeof(ushort));          // [NPAD,128] bf16
    ushort* h2 = (ushort*)region0;                                             // [N,256] bf16
    ushort* h1 = (ushort*)p;            p += (size_t)N * H * sizeof(ushort);   // [N,256] bf16
    ushort* S2 = (ushort*)p;            p += (size_t)NPAD * H * sizeof(ushort);// [NPAD,256] bf16
    int*   deg = (int*)p;               p += (size_t)N * sizeof(int);
    int*   off = (int*)p;               p += (size_t)(N + 1) * sizeof(int) + 12;
    int*   cur = (int*)p;               p += (size_t)N * sizeof(int);
    int*   bsum= (int*)p;               p += 256 * sizeof(int);
    uint2* edges=(uint2*)p;             p += (size_t)E * sizeof(uint2);        // packed (src,w)
    ushort* Wt1= (ushort*)p;            p += (size_t)H * F * sizeof(ushort);   // [256,128]
    ushort* Wt2= (ushort*)p;            p += (size_t)H * H * sizeof(ushort);   // [256,256]

    // ---- prep (x->bf16, deg hist, W^T) + CSR build ----
    hipMemsetAsync(deg, 0, (size_t)N * sizeof(int), stream);
    prep<<<9887, 256, 0, stream>>>(x, xh, edst, deg, W1, Wt1, W2, Wt2, E);
    scan_block<<<NB, 256, 0, stream>>>(deg, off, bsum, N);
    scan_apply<<<NB, 256, 0, stream>>>(off, bsum, cur, N, E, NB);
    csr_fill<<<(E + 255) / 256, 256, 0, stream>>>(esrc, edst, ew, cur, edges, E);

    // ---- layer 1: S1 = A@x ; h1 = relu(S1@W1 + b1) ----
    spmm128<<<(N + 3) / 4, 256, 0, stream>>>(xh, off, edges, S1, N);
    gemm_tile<128, true><<<dim3(NPAD / 128, 2), 256, 0, stream>>>(S1, Wt1, b1, h1, N);

    // ---- layer 2: S2 = A@h1 ; h2 = relu(S2@W2 + b2), h2 bf16 ----
    spmm256<<<(N + 3) / 4, 256, 0, stream>>>(h1, off, edges, S2, N);
    gemm_tile<256, true><<<dim3(NPAD / 128, 2), 256, 0, stream>>>(S2, Wt2, b2, h2, N);

    // ---- fused pool + head (bf16 input) ----
    pool_head<<<G, 256, 0, stream>>>(h2, seg, Wd, bd, Wo, bo, out, N);
}

// Round 9
// 356.794 us; speedup vs baseline: 1.1125x; 1.1125x over previous
//
#include <hip/hip_runtime.h>
#include <hip/hip_bf16.h>

// ---------------------------------------------------------------------------
// TwoLayerGCN. Round 9: un-fuse pool from head. R8's fused pool_head ran
// 128 blocks (0.5/CU, occ 4.7%) with 1 load in flight -> 71us @ 197 GB/s.
// pool_seg: 391 blocks x 256 feat-threads, x4-row unroll, register accum,
// atomic flush at segment boundaries (seg sorted). head: 128 blocks.
// h2 stays bf16.
// ---------------------------------------------------------------------------

typedef short v8s __attribute__((ext_vector_type(8)));
typedef float v4f __attribute__((ext_vector_type(4)));

__device__ inline unsigned bf16u(float f) {           // fp32 -> bf16 bits (RNE)
    unsigned u = __builtin_bit_cast(unsigned, f);
    return (u + 0x7fffu + ((u >> 16) & 1u)) >> 16;
}
__device__ inline float bflo(unsigned v) { return __builtin_bit_cast(float, v << 16); }
__device__ inline float bfhi(unsigned v) { return __builtin_bit_cast(float, v & 0xffff0000u); }
__device__ inline float f32bits(unsigned v) { return __builtin_bit_cast(float, v); }
__device__ inline float bfs(ushort v) { return __builtin_bit_cast(float, (unsigned)v << 16); }

// ------------------- fused prep: x->bf16, degree hist, W^T -------------------
__global__ __launch_bounds__(256) void prep(
    const float* __restrict__ x, ushort* __restrict__ xh,
    const int* __restrict__ dst, int* __restrict__ deg,
    const float* __restrict__ W1, ushort* __restrict__ Wt1,
    const float* __restrict__ W2, ushort* __restrict__ Wt2, int E)
{
    int b = blockIdx.x;
    int t = threadIdx.x;
    if (b < 6250) {
        int i = b * 256 + t;                 // n4 = 1600000
        if (i < 1600000) {
            float4 v = ((const float4*)x)[i];
            unsigned lo = (bf16u(v.y) << 16) | bf16u(v.x);
            unsigned hi = (bf16u(v.w) << 16) | bf16u(v.z);
            ((uint2*)xh)[i] = make_uint2(lo, hi);
        }
    } else if (b < 9375) {
        int e = (b - 6250) * 256 + t;
        if (e < E) atomicAdd(&deg[dst[e]], 1);
    } else if (b < 9631) {
        int n = b - 9375;
        if (t < 128) Wt1[n * 128 + t] = (ushort)bf16u(W1[t * 256 + n]);
    } else {
        int n = b - 9631;
        Wt2[n * 256 + t] = (ushort)bf16u(W2[t * 256 + n]);
    }
}

// ---------------- CSR-by-destination build (once per launch) ----------------

__global__ __launch_bounds__(256) void scan_block(
    const int* __restrict__ deg, int* __restrict__ off,
    int* __restrict__ blocksums, int n)
{
    __shared__ int s[256];
    int tid = threadIdx.x;
    int gid = blockIdx.x * 256 + tid;
    int v = (gid < n) ? deg[gid] : 0;
    s[tid] = v;
    __syncthreads();
    for (int o = 1; o < 256; o <<= 1) {
        int t = (tid >= o) ? s[tid - o] : 0;
        __syncthreads();
        s[tid] += t;
        __syncthreads();
    }
    if (gid < n) off[gid] = s[tid] - v;
    if (tid == 255) blocksums[blockIdx.x] = s[255];
}

__global__ __launch_bounds__(256) void scan_apply(
    int* __restrict__ off, const int* __restrict__ blocksums,
    int* __restrict__ cursor, int n, int E, int nb)
{
    __shared__ int s[256];
    int tid = threadIdx.x;
    int v = (tid < nb) ? blocksums[tid] : 0;
    s[tid] = v;
    __syncthreads();
    for (int o = 1; o < 256; o <<= 1) {
        int t = (tid >= o) ? s[tid - o] : 0;
        __syncthreads();
        s[tid] += t;
        __syncthreads();
    }
    int b = blockIdx.x;
    int boff = (b == 0) ? 0 : s[b - 1];
    int gid = b * 256 + tid;
    if (gid < n) {
        int w = off[gid] + boff;
        off[gid] = w;
        cursor[gid] = w;
    }
    if (gid == 0) off[n] = E;
}

__global__ __launch_bounds__(256) void csr_fill(
    const int* __restrict__ src, const int* __restrict__ dst,
    const float* __restrict__ w, int* __restrict__ cursor,
    uint2* __restrict__ edges, int E)
{
    int e = blockIdx.x * 256 + threadIdx.x;
    if (e >= E) return;
    int d = dst[e];
    int p = atomicAdd(&cursor[d], 1);
    edges[p] = make_uint2((unsigned)src[e],
                          __builtin_bit_cast(unsigned, w[e]));
}

// ----------------------- gather SpMM (bf16 in/out) --------------------------
__global__ __launch_bounds__(256) void spmm128(
    const ushort* __restrict__ xh, const int* __restrict__ off,
    const uint2* __restrict__ edges, ushort* __restrict__ S, int n)
{
    int node = blockIdx.x * 4 + (threadIdx.x >> 6);
    if (node >= n) return;
    int lane = threadIdx.x & 63;
    const unsigned* base = (const unsigned*)xh;   // row stride 64 uints
    int e0 = off[node], e1 = off[node + 1];
    float a0 = 0.f, a1 = 0.f;
    int e = e0;
    for (; e + 4 <= e1; e += 4) {
        uint2 ed0 = edges[e],     ed1 = edges[e + 1];
        uint2 ed2 = edges[e + 2], ed3 = edges[e + 3];
        float w0 = f32bits(ed0.y), w1 = f32bits(ed1.y);
        float w2 = f32bits(ed2.y), w3 = f32bits(ed3.y);
        unsigned v0 = base[(size_t)ed0.x * 64 + lane];
        unsigned v1 = base[(size_t)ed1.x * 64 + lane];
        unsigned v2 = base[(size_t)ed2.x * 64 + lane];
        unsigned v3 = base[(size_t)ed3.x * 64 + lane];
        a0 += bflo(v0) * w0 + bflo(v1) * w1 + bflo(v2) * w2 + bflo(v3) * w3;
        a1 += bfhi(v0) * w0 + bfhi(v1) * w1 + bfhi(v2) * w2 + bfhi(v3) * w3;
    }
    for (; e < e1; e++) {
        uint2 ed = edges[e];
        float w0 = f32bits(ed.y);
        unsigned v0 = base[(size_t)ed.x * 64 + lane];
        a0 += bflo(v0) * w0;
        a1 += bfhi(v0) * w0;
    }
    ((unsigned*)S)[(size_t)node * 64 + lane] = (bf16u(a1) << 16) | bf16u(a0);
}

__global__ __launch_bounds__(256) void spmm256(
    const ushort* __restrict__ hh, const int* __restrict__ off,
    const uint2* __restrict__ edges, ushort* __restrict__ S, int n)
{
    int node = blockIdx.x * 4 + (threadIdx.x >> 6);
    if (node >= n) return;
    int lane = threadIdx.x & 63;
    const uint2* base = (const uint2*)hh;          // row stride 64 uint2
    int e0 = off[node], e1 = off[node + 1];
    float a0 = 0.f, a1 = 0.f, a2 = 0.f, a3 = 0.f;
    int e = e0;
    for (; e + 4 <= e1; e += 4) {
        uint2 ed0 = edges[e],     ed1 = edges[e + 1];
        uint2 ed2 = edges[e + 2], ed3 = edges[e + 3];
        float w0 = f32bits(ed0.y), w1 = f32bits(ed1.y);
        float w2 = f32bits(ed2.y), w3 = f32bits(ed3.y);
        uint2 v0 = base[(size_t)ed0.x * 64 + lane];
        uint2 v1 = base[(size_t)ed1.x * 64 + lane];
        uint2 v2 = base[(size_t)ed2.x * 64 + lane];
        uint2 v3 = base[(size_t)ed3.x * 64 + lane];
        a0 += bflo(v0.x) * w0 + bflo(v1.x) * w1 + bflo(v2.x) * w2 + bflo(v3.x) * w3;
        a1 += bfhi(v0.x) * w0 + bfhi(v1.x) * w1 + bfhi(v2.x) * w2 + bfhi(v3.x) * w3;
        a2 += bflo(v0.y) * w0 + bflo(v1.y) * w1 + bflo(v2.y) * w2 + bflo(v3.y) * w3;
        a3 += bfhi(v0.y) * w0 + bfhi(v1.y) * w1 + bfhi(v2.y) * w2 + bfhi(v3.y) * w3;
    }
    for (; e < e1; e++) {
        uint2 ed = edges[e];
        float w0 = f32bits(ed.y);
        uint2 v0 = base[(size_t)ed.x * 64 + lane];
        a0 += bflo(v0.x) * w0;
        a1 += bfhi(v0.x) * w0;
        a2 += bflo(v0.y) * w0;
        a3 += bfhi(v0.y) * w0;
    }
    uint2 o;
    o.x = (bf16u(a1) << 16) | bf16u(a0);
    o.y = (bf16u(a3) << 16) | bf16u(a2);
    ((uint2*)S)[(size_t)node * 64 + lane] = o;
}

// ----------------------- LDS-tiled MFMA bf16 GEMM ---------------------------
template <int K, bool BF16OUT>
__global__ __launch_bounds__(256) void gemm_tile(
    const ushort* __restrict__ A, const ushort* __restrict__ Wt,
    const float* __restrict__ bias, void* __restrict__ out, int M)
{
    __shared__ __align__(16) ushort As[128 * 32];
    __shared__ __align__(16) ushort Bs[128 * 32];

    const int tid = threadIdx.x;
    const int bm = blockIdx.x * 128;
    const int bn = blockIdx.y * 128;
    const int wave = tid >> 6, lane = tid & 63;
    const int wm = wave >> 1, wn = wave & 1;
    const int r = lane & 15, q = lane >> 4;

    const int o0 = tid * 16;
    const int row0 = o0 >> 6;
    const int kb0 = o0 & 63;

    const char* Ab = (const char*)A;
    const char* Bb = (const char*)Wt;

    uint4 ra0, ra1, rb0, rb1;
    ra0 = *(const uint4*)(Ab + ((size_t)(bm + row0)      * K) * 2 + kb0);
    ra1 = *(const uint4*)(Ab + ((size_t)(bm + row0 + 64) * K) * 2 + kb0);
    rb0 = *(const uint4*)(Bb + ((size_t)(bn + row0)      * K) * 2 + kb0);
    rb1 = *(const uint4*)(Bb + ((size_t)(bn + row0 + 64) * K) * 2 + kb0);

    v4f acc[4][4];
    #pragma unroll
    for (int i = 0; i < 4; i++)
        #pragma unroll
        for (int j = 0; j < 4; j++) acc[i][j] = (v4f){0.f, 0.f, 0.f, 0.f};

    const int NK = K / 32;
    for (int ks = 0; ks < NK; ks++) {
        __syncthreads();
        *(uint4*)((char*)As + o0)        = ra0;
        *(uint4*)((char*)As + o0 + 4096) = ra1;
        *(uint4*)((char*)Bs + o0)        = rb0;
        *(uint4*)((char*)Bs + o0 + 4096) = rb1;
        if (ks + 1 < NK) {
            const int kof = (ks + 1) * 64;
            ra0 = *(const uint4*)(Ab + ((size_t)(bm + row0)      * K) * 2 + kof + kb0);
            ra1 = *(const uint4*)(Ab + ((size_t)(bm + row0 + 64) * K) * 2 + kof + kb0);
            rb0 = *(const uint4*)(Bb + ((size_t)(bn + row0)      * K) * 2 + kof + kb0);
            rb1 = *(const uint4*)(Bb + ((size_t)(bn + row0 + 64) * K) * 2 + kof + kb0);
        }
        __syncthreads();

        v8s af[4], bf[4];
        #pragma unroll
        for (int i = 0; i < 4; i++)
            af[i] = *(const v8s*)(As + (wm * 64 + i * 16 + r) * 32 + q * 8);
        #pragma unroll
        for (int j = 0; j < 4; j++)
            bf[j] = *(const v8s*)(Bs + (wn * 64 + j * 16 + r) * 32 + q * 8);
        #pragma unroll
        for (int i = 0; i < 4; i++)
            #pragma unroll
            for (int j = 0; j < 4; j++)
                acc[i][j] = __builtin_amdgcn_mfma_f32_16x16x32_bf16(
                    af[i], bf[j], acc[i][j], 0, 0, 0);
    }

    #pragma unroll
    for (int j = 0; j < 4; j++) {
        int col = bn + wn * 64 + j * 16 + r;
        float b = bias[col];
        #pragma unroll
        for (int i = 0; i < 4; i++) {
            #pragma unroll
            for (int ii = 0; ii < 4; ii++) {
                int row = bm + wm * 64 + i * 16 + q * 4 + ii;
                if (row < M) {
                    float v = fmaxf(acc[i][j][ii] + b, 0.f);
                    if constexpr (BF16OUT)
                        ((ushort*)out)[(size_t)row * 256 + col] = (ushort)bf16u(v);
                    else
                        ((float*)out)[(size_t)row * 256 + col] = v;
                }
            }
        }
    }
}

// ------------------------------- pool + head --------------------------------
// h2 bf16 [N,256]. Block b: 128-row chunk, thread = feature. x4-row unroll,
// register accum within a segment (seg sorted), atomicAdd flush at
// boundaries into fp32 g[128][256].
__global__ __launch_bounds__(256) void pool_seg(
    const ushort* __restrict__ h2, const int* __restrict__ seg,
    float* __restrict__ g, int n_nodes)
{
    int f = threadIdx.x;
    int n0 = blockIdx.x * 128;
    int n1 = min(n0 + 128, n_nodes);
    float acc = 0.f;
    int cur = seg[n0];
    int nn = n0;
    while (nn < n1) {
        // find run end: same segment and within x4 window
        if (nn + 4 <= n1 && seg[nn + 3] == cur) {
            float t0 = bfs(h2[(size_t)nn * 256 + f]);
            float t1 = bfs(h2[(size_t)(nn + 1) * 256 + f]);
            float t2 = bfs(h2[(size_t)(nn + 2) * 256 + f]);
            float t3 = bfs(h2[(size_t)(nn + 3) * 256 + f]);
            acc += (t0 + t1) + (t2 + t3);
            nn += 4;
        } else {
            int s = seg[nn];
            if (s != cur) {
                atomicAdd(&g[(size_t)cur * 256 + f], acc);
                acc = 0.f;
                cur = s;
            }
            acc += bfs(h2[(size_t)nn * 256 + f]);
            nn++;
        }
    }
    atomicAdd(&g[(size_t)cur * 256 + f], acc);
}

__global__ __launch_bounds__(256) void head(
    const float* __restrict__ g, const float* __restrict__ Wd,
    const float* __restrict__ bd, const float* __restrict__ Wo,
    const float* __restrict__ bo, float* __restrict__ out)
{
    __shared__ float gr[256];
    int j = threadIdx.x;
    int gi = blockIdx.x;
    gr[j] = g[(size_t)gi * 256 + j];
    __syncthreads();
    float a2 = bd[j];
    for (int k = 0; k < 256; k++)
        a2 += gr[k] * Wd[(size_t)k * 256 + j];
    a2 = fmaxf(a2, 0.f);

    float v = a2 * Wo[j];
    #pragma unroll
    for (int off = 32; off > 0; off >>= 1)
        v += __shfl_down(v, off, 64);
    __shared__ float partial[4];
    if ((j & 63) == 0) partial[j >> 6] = v;
    __syncthreads();
    if (j == 0)
        out[gi] = partial[0] + partial[1] + partial[2] + partial[3] + bo[0];
}

extern "C" void kernel_launch(void* const* d_in, const int* in_sizes, int n_in,
                              void* d_out, int out_size, void* d_ws, size_t ws_size,
                              hipStream_t stream) {
    const float* x   = (const float*)d_in[0];
    const int*   esrc= (const int*)  d_in[1];
    const int*   edst= (const int*)  d_in[2];
    const float* ew  = (const float*)d_in[3];
    const int*   seg = (const int*)  d_in[4];
    const float* W1  = (const float*)d_in[5];
    const float* b1  = (const float*)d_in[6];
    const float* W2  = (const float*)d_in[7];
    const float* b2  = (const float*)d_in[8];
    const float* Wd  = (const float*)d_in[9];
    const float* bd  = (const float*)d_in[10];
    const float* Wo  = (const float*)d_in[11];
    const float* bo  = (const float*)d_in[12];
    float* out = (float*)d_out;

    const int N = 50000, E = 800000, G = 128, H = 256, F = 128;
    const int NPAD = 50048;            // 391 * 128
    const int NB = (N + 255) / 256;    // 196

    // workspace; region0 reused: {xh, S1} early, h2 (bf16) late
    char* p = (char*)d_ws;
    char* region0 = p;                  p += (size_t)N * H * sizeof(float);    // 51.2 MB
    ushort* xh = (ushort*)region0;                                             // [N,128] bf16
    ushort* S1 = (ushort*)(region0 + (size_t)N * F * sizeof(ushort));          // [NPAD,128] bf16
    ushort* h2 = (ushort*)region0;                                             // [N,256] bf16
    ushort* h1 = (ushort*)p;            p += (size_t)N * H * sizeof(ushort);   // [N,256] bf16
    ushort* S2 = (ushort*)p;            p += (size_t)NPAD * H * sizeof(ushort);// [NPAD,256] bf16
    float* g   = (float*)p;             p += (size_t)G * H * sizeof(float);
    int*   deg = (int*)p;               p += (size_t)N * sizeof(int);
    int*   off = (int*)p;               p += (size_t)(N + 1) * sizeof(int) + 12;
    int*   cur = (int*)p;               p += (size_t)N * sizeof(int);
    int*   bsum= (int*)p;               p += 256 * sizeof(int);
    uint2* edges=(uint2*)p;             p += (size_t)E * sizeof(uint2);        // packed (src,w)
    ushort* Wt1= (ushort*)p;            p += (size_t)H * F * sizeof(ushort);   // [256,128]
    ushort* Wt2= (ushort*)p;            p += (size_t)H * H * sizeof(ushort);   // [256,256]

    // ---- prep (x->bf16, deg hist, W^T) + CSR build ----
    hipMemsetAsync(deg, 0, (size_t)N * sizeof(int), stream);
    hipMemsetAsync(g, 0, (size_t)G * H * sizeof(float), stream);
    prep<<<9887, 256, 0, stream>>>(x, xh, edst, deg, W1, Wt1, W2, Wt2, E);
    scan_block<<<NB, 256, 0, stream>>>(deg, off, bsum, N);
    scan_apply<<<NB, 256, 0, stream>>>(off, bsum, cur, N, E, NB);
    csr_fill<<<(E + 255) / 256, 256, 0, stream>>>(esrc, edst, ew, cur, edges, E);

    // ---- layer 1: S1 = A@x ; h1 = relu(S1@W1 + b1) ----
    spmm128<<<(N + 3) / 4, 256, 0, stream>>>(xh, off, edges, S1, N);
    gemm_tile<128, true><<<dim3(NPAD / 128, 2), 256, 0, stream>>>(S1, Wt1, b1, h1, N);

    // ---- layer 2: S2 = A@h1 ; h2 = relu(S2@W2 + b2), h2 bf16 ----
    spmm256<<<(N + 3) / 4, 256, 0, stream>>>(h1, off, edges, S2, N);
    gemm_tile<256, true><<<dim3(NPAD / 128, 2), 256, 0, stream>>>(S2, Wt2, b2, h2, N);

    // ---- pool (391 blocks) + head (128 blocks) ----
    pool_seg<<<(N + 127) / 128, 256, 0, stream>>>(h2, seg, g, N);
    head<<<G, 256, 0, stream>>>(g, Wd, bd, Wo, bo, out);
}

// Round 10
// 325.635 us; speedup vs baseline: 1.2189x; 1.0957x over previous
//
#include <hip/hip_runtime.h>
#include <hip/hip_bf16.h>

// ---------------------------------------------------------------------------
// TwoLayerGCN. Round 10: eliminate h2 entirely - pool fused into the
// gemm<256> epilogue (bias+relu in regs -> per-segment predicated lane sums
// -> shfl_xor reduce over q-groups -> atomicAdd into g). Saves h2 write
// (25.6MB) + pool read (25.6MB) + 2 dispatches. g zeroed inside csr_fill.
// spmm256 is at its random-gather path ceiling (R7/R9: 45% peak, MLP
// ~5x over Little's-law need, fetch near unique-rows-per-XCD floor).
// ---------------------------------------------------------------------------

typedef short v8s __attribute__((ext_vector_type(8)));
typedef float v4f __attribute__((ext_vector_type(4)));

__device__ inline unsigned bf16u(float f) {           // fp32 -> bf16 bits (RNE)
    unsigned u = __builtin_bit_cast(unsigned, f);
    return (u + 0x7fffu + ((u >> 16) & 1u)) >> 16;
}
__device__ inline float bflo(unsigned v) { return __builtin_bit_cast(float, v << 16); }
__device__ inline float bfhi(unsigned v) { return __builtin_bit_cast(float, v & 0xffff0000u); }
__device__ inline float f32bits(unsigned v) { return __builtin_bit_cast(float, v); }

// ------------------- fused prep: x->bf16, degree hist, W^T -------------------
__global__ __launch_bounds__(256) void prep(
    const float* __restrict__ x, ushort* __restrict__ xh,
    const int* __restrict__ dst, int* __restrict__ deg,
    const float* __restrict__ W1, ushort* __restrict__ Wt1,
    const float* __restrict__ W2, ushort* __restrict__ Wt2, int E)
{
    int b = blockIdx.x;
    int t = threadIdx.x;
    if (b < 6250) {
        int i = b * 256 + t;                 // n4 = 1600000
        if (i < 1600000) {
            float4 v = ((const float4*)x)[i];
            unsigned lo = (bf16u(v.y) << 16) | bf16u(v.x);
            unsigned hi = (bf16u(v.w) << 16) | bf16u(v.z);
            ((uint2*)xh)[i] = make_uint2(lo, hi);
        }
    } else if (b < 9375) {
        int e = (b - 6250) * 256 + t;
        if (e < E) atomicAdd(&deg[dst[e]], 1);
    } else if (b < 9631) {
        int n = b - 9375;
        if (t < 128) Wt1[n * 128 + t] = (ushort)bf16u(W1[t * 256 + n]);
    } else {
        int n = b - 9631;
        Wt2[n * 256 + t] = (ushort)bf16u(W2[t * 256 + n]);
    }
}

// ---------------- CSR-by-destination build (once per launch) ----------------

__global__ __launch_bounds__(256) void scan_block(
    const int* __restrict__ deg, int* __restrict__ off,
    int* __restrict__ blocksums, int n)
{
    __shared__ int s[256];
    int tid = threadIdx.x;
    int gid = blockIdx.x * 256 + tid;
    int v = (gid < n) ? deg[gid] : 0;
    s[tid] = v;
    __syncthreads();
    for (int o = 1; o < 256; o <<= 1) {
        int t = (tid >= o) ? s[tid - o] : 0;
        __syncthreads();
        s[tid] += t;
        __syncthreads();
    }
    if (gid < n) off[gid] = s[tid] - v;
    if (tid == 255) blocksums[blockIdx.x] = s[255];
}

__global__ __launch_bounds__(256) void scan_apply(
    int* __restrict__ off, const int* __restrict__ blocksums,
    int* __restrict__ cursor, int n, int E, int nb)
{
    __shared__ int s[256];
    int tid = threadIdx.x;
    int v = (tid < nb) ? blocksums[tid] : 0;
    s[tid] = v;
    __syncthreads();
    for (int o = 1; o < 256; o <<= 1) {
        int t = (tid >= o) ? s[tid - o] : 0;
        __syncthreads();
        s[tid] += t;
        __syncthreads();
    }
    int b = blockIdx.x;
    int boff = (b == 0) ? 0 : s[b - 1];
    int gid = b * 256 + tid;
    if (gid < n) {
        int w = off[gid] + boff;
        off[gid] = w;
        cursor[gid] = w;
    }
    if (gid == 0) off[n] = E;
}

// also zeroes g[128*256] (needed before gemm_pool's atomics, much later)
__global__ __launch_bounds__(256) void csr_fill(
    const int* __restrict__ src, const int* __restrict__ dst,
    const float* __restrict__ w, int* __restrict__ cursor,
    uint2* __restrict__ edges, float* __restrict__ g, int E)
{
    int b = blockIdx.x, t = threadIdx.x;
    if (b < 128) g[b * 256 + t] = 0.f;
    int e = b * 256 + t;
    if (e >= E) return;
    int d = dst[e];
    int p = atomicAdd(&cursor[d], 1);
    edges[p] = make_uint2((unsigned)src[e],
                          __builtin_bit_cast(unsigned, w[e]));
}

// ----------------------- gather SpMM (bf16 in/out) --------------------------
__global__ __launch_bounds__(256) void spmm128(
    const ushort* __restrict__ xh, const int* __restrict__ off,
    const uint2* __restrict__ edges, ushort* __restrict__ S, int n)
{
    int node = blockIdx.x * 4 + (threadIdx.x >> 6);
    if (node >= n) return;
    int lane = threadIdx.x & 63;
    const unsigned* base = (const unsigned*)xh;   // row stride 64 uints
    int e0 = off[node], e1 = off[node + 1];
    float a0 = 0.f, a1 = 0.f;
    int e = e0;
    for (; e + 4 <= e1; e += 4) {
        uint2 ed0 = edges[e],     ed1 = edges[e + 1];
        uint2 ed2 = edges[e + 2], ed3 = edges[e + 3];
        float w0 = f32bits(ed0.y), w1 = f32bits(ed1.y);
        float w2 = f32bits(ed2.y), w3 = f32bits(ed3.y);
        unsigned v0 = base[(size_t)ed0.x * 64 + lane];
        unsigned v1 = base[(size_t)ed1.x * 64 + lane];
        unsigned v2 = base[(size_t)ed2.x * 64 + lane];
        unsigned v3 = base[(size_t)ed3.x * 64 + lane];
        a0 += bflo(v0) * w0 + bflo(v1) * w1 + bflo(v2) * w2 + bflo(v3) * w3;
        a1 += bfhi(v0) * w0 + bfhi(v1) * w1 + bfhi(v2) * w2 + bfhi(v3) * w3;
    }
    for (; e < e1; e++) {
        uint2 ed = edges[e];
        float w0 = f32bits(ed.y);
        unsigned v0 = base[(size_t)ed.x * 64 + lane];
        a0 += bflo(v0) * w0;
        a1 += bfhi(v0) * w0;
    }
    ((unsigned*)S)[(size_t)node * 64 + lane] = (bf16u(a1) << 16) | bf16u(a0);
}

__global__ __launch_bounds__(256) void spmm256(
    const ushort* __restrict__ hh, const int* __restrict__ off,
    const uint2* __restrict__ edges, ushort* __restrict__ S, int n)
{
    int node = blockIdx.x * 4 + (threadIdx.x >> 6);
    if (node >= n) return;
    int lane = threadIdx.x & 63;
    const uint2* base = (const uint2*)hh;          // row stride 64 uint2
    int e0 = off[node], e1 = off[node + 1];
    float a0 = 0.f, a1 = 0.f, a2 = 0.f, a3 = 0.f;
    int e = e0;
    for (; e + 4 <= e1; e += 4) {
        uint2 ed0 = edges[e],     ed1 = edges[e + 1];
        uint2 ed2 = edges[e + 2], ed3 = edges[e + 3];
        float w0 = f32bits(ed0.y), w1 = f32bits(ed1.y);
        float w2 = f32bits(ed2.y), w3 = f32bits(ed3.y);
        uint2 v0 = base[(size_t)ed0.x * 64 + lane];
        uint2 v1 = base[(size_t)ed1.x * 64 + lane];
        uint2 v2 = base[(size_t)ed2.x * 64 + lane];
        uint2 v3 = base[(size_t)ed3.x * 64 + lane];
        a0 += bflo(v0.x) * w0 + bflo(v1.x) * w1 + bflo(v2.x) * w2 + bflo(v3.x) * w3;
        a1 += bfhi(v0.x) * w0 + bfhi(v1.x) * w1 + bfhi(v2.x) * w2 + bfhi(v3.x) * w3;
        a2 += bflo(v0.y) * w0 + bflo(v1.y) * w1 + bflo(v2.y) * w2 + bflo(v3.y) * w3;
        a3 += bfhi(v0.y) * w0 + bfhi(v1.y) * w1 + bfhi(v2.y) * w2 + bfhi(v3.y) * w3;
    }
    for (; e < e1; e++) {
        uint2 ed = edges[e];
        float w0 = f32bits(ed.y);
        uint2 v0 = base[(size_t)ed.x * 64 + lane];
        a0 += bflo(v0.x) * w0;
        a1 += bfhi(v0.x) * w0;
        a2 += bflo(v0.y) * w0;
        a3 += bfhi(v0.y) * w0;
    }
    uint2 o;
    o.x = (bf16u(a1) << 16) | bf16u(a0);
    o.y = (bf16u(a3) << 16) | bf16u(a2);
    ((uint2*)S)[(size_t)node * 64 + lane] = o;
}

// ----------------------- LDS-tiled MFMA bf16 GEMM ---------------------------
// POOL=false: store relu(A@W+b) to out (bf16 or f32 per BF16OUT).
// POOL=true : no store; pool rows by segment id into g[128][256] via atomics
//             (seg sorted; a 128-row chunk spans ~1-3 segments).
template <int K, bool BF16OUT, bool POOL>
__global__ __launch_bounds__(256) void gemm_tile(
    const ushort* __restrict__ A, const ushort* __restrict__ Wt,
    const float* __restrict__ bias, void* __restrict__ out,
    const int* __restrict__ seg, float* __restrict__ g, int M)
{
    __shared__ __align__(16) ushort As[128 * 32];
    __shared__ __align__(16) ushort Bs[128 * 32];
    __shared__ int segsh[128];

    const int tid = threadIdx.x;
    const int bm = blockIdx.x * 128;
    const int bn = blockIdx.y * 128;
    const int wave = tid >> 6, lane = tid & 63;
    const int wm = wave >> 1, wn = wave & 1;
    const int r = lane & 15, q = lane >> 4;

    if (POOL && tid < 128) {
        int gr = bm + tid;
        segsh[tid] = (gr < M) ? seg[gr] : 0x7fffffff;   // sentinel: never matches
    }

    const int o0 = tid * 16;
    const int row0 = o0 >> 6;
    const int kb0 = o0 & 63;

    const char* Ab = (const char*)A;
    const char* Bb = (const char*)Wt;

    uint4 ra0, ra1, rb0, rb1;
    ra0 = *(const uint4*)(Ab + ((size_t)(bm + row0)      * K) * 2 + kb0);
    ra1 = *(const uint4*)(Ab + ((size_t)(bm + row0 + 64) * K) * 2 + kb0);
    rb0 = *(const uint4*)(Bb + ((size_t)(bn + row0)      * K) * 2 + kb0);
    rb1 = *(const uint4*)(Bb + ((size_t)(bn + row0 + 64) * K) * 2 + kb0);

    v4f acc[4][4];
    #pragma unroll
    for (int i = 0; i < 4; i++)
        #pragma unroll
        for (int j = 0; j < 4; j++) acc[i][j] = (v4f){0.f, 0.f, 0.f, 0.f};

    const int NK = K / 32;
    for (int ks = 0; ks < NK; ks++) {
        __syncthreads();
        *(uint4*)((char*)As + o0)        = ra0;
        *(uint4*)((char*)As + o0 + 4096) = ra1;
        *(uint4*)((char*)Bs + o0)        = rb0;
        *(uint4*)((char*)Bs + o0 + 4096) = rb1;
        if (ks + 1 < NK) {
            const int kof = (ks + 1) * 64;
            ra0 = *(const uint4*)(Ab + ((size_t)(bm + row0)      * K) * 2 + kof + kb0);
            ra1 = *(const uint4*)(Ab + ((size_t)(bm + row0 + 64) * K) * 2 + kof + kb0);
            rb0 = *(const uint4*)(Bb + ((size_t)(bn + row0)      * K) * 2 + kof + kb0);
            rb1 = *(const uint4*)(Bb + ((size_t)(bn + row0 + 64) * K) * 2 + kof + kb0);
        }
        __syncthreads();

        v8s af[4], bf[4];
        #pragma unroll
        for (int i = 0; i < 4; i++)
            af[i] = *(const v8s*)(As + (wm * 64 + i * 16 + r) * 32 + q * 8);
        #pragma unroll
        for (int j = 0; j < 4; j++)
            bf[j] = *(const v8s*)(Bs + (wn * 64 + j * 16 + r) * 32 + q * 8);
        #pragma unroll
        for (int i = 0; i < 4; i++)
            #pragma unroll
            for (int j = 0; j < 4; j++)
                acc[i][j] = __builtin_amdgcn_mfma_f32_16x16x32_bf16(
                    af[i], bf[j], acc[i][j], 0, 0, 0);
    }

    if constexpr (POOL) {
        // bias + relu in place
        #pragma unroll
        for (int j = 0; j < 4; j++) {
            float b = bias[bn + wn * 64 + j * 16 + r];
            #pragma unroll
            for (int i = 0; i < 4; i++)
                #pragma unroll
                for (int ii = 0; ii < 4; ii++)
                    acc[i][j][ii] = fmaxf(acc[i][j][ii] + b, 0.f);
        }
        // per-lane row segment ids (16 rows per lane)
        int myseg[16];
        #pragma unroll
        for (int i = 0; i < 4; i++)
            #pragma unroll
            for (int ii = 0; ii < 4; ii++)
                myseg[i * 4 + ii] = segsh[wm * 64 + i * 16 + q * 4 + ii];
        int s_lo = segsh[0];
        int s_hi = segsh[min(127, M - 1 - bm)];
        for (int s = s_lo; s <= s_hi; s++) {
            #pragma unroll
            for (int j = 0; j < 4; j++) {
                float p = 0.f;
                #pragma unroll
                for (int i = 0; i < 4; i++)
                    #pragma unroll
                    for (int ii = 0; ii < 4; ii++)
                        if (myseg[i * 4 + ii] == s) p += acc[i][j][ii];
                p += __shfl_xor(p, 16, 64);
                p += __shfl_xor(p, 32, 64);
                if (lane < 16)
                    atomicAdd(&g[s * 256 + bn + wn * 64 + j * 16 + r], p);
            }
        }
    } else {
        #pragma unroll
        for (int j = 0; j < 4; j++) {
            int col = bn + wn * 64 + j * 16 + r;
            float b = bias[col];
            #pragma unroll
            for (int i = 0; i < 4; i++) {
                #pragma unroll
                for (int ii = 0; ii < 4; ii++) {
                    int row = bm + wm * 64 + i * 16 + q * 4 + ii;
                    if (row < M) {
                        float v = fmaxf(acc[i][j][ii] + b, 0.f);
                        if constexpr (BF16OUT)
                            ((ushort*)out)[(size_t)row * 256 + col] = (ushort)bf16u(v);
                        else
                            ((float*)out)[(size_t)row * 256 + col] = v;
                    }
                }
            }
        }
    }
}

// ---------------------------------- head ------------------------------------
__global__ __launch_bounds__(256) void head(
    const float* __restrict__ g, const float* __restrict__ Wd,
    const float* __restrict__ bd, const float* __restrict__ Wo,
    const float* __restrict__ bo, float* __restrict__ out)
{
    __shared__ float gr[256];
    int j = threadIdx.x;
    int gi = blockIdx.x;
    gr[j] = g[(size_t)gi * 256 + j];
    __syncthreads();
    float a2 = bd[j];
    for (int k = 0; k < 256; k++)
        a2 += gr[k] * Wd[(size_t)k * 256 + j];
    a2 = fmaxf(a2, 0.f);

    float v = a2 * Wo[j];
    #pragma unroll
    for (int off = 32; off > 0; off >>= 1)
        v += __shfl_down(v, off, 64);
    __shared__ float partial[4];
    if ((j & 63) == 0) partial[j >> 6] = v;
    __syncthreads();
    if (j == 0)
        out[gi] = partial[0] + partial[1] + partial[2] + partial[3] + bo[0];
}

extern "C" void kernel_launch(void* const* d_in, const int* in_sizes, int n_in,
                              void* d_out, int out_size, void* d_ws, size_t ws_size,
                              hipStream_t stream) {
    const float* x   = (const float*)d_in[0];
    const int*   esrc= (const int*)  d_in[1];
    const int*   edst= (const int*)  d_in[2];
    const float* ew  = (const float*)d_in[3];
    const int*   seg = (const int*)  d_in[4];
    const float* W1  = (const float*)d_in[5];
    const float* b1  = (const float*)d_in[6];
    const float* W2  = (const float*)d_in[7];
    const float* b2  = (const float*)d_in[8];
    const float* Wd  = (const float*)d_in[9];
    const float* bd  = (const float*)d_in[10];
    const float* Wo  = (const float*)d_in[11];
    const float* bo  = (const float*)d_in[12];
    float* out = (float*)d_out;

    const int N = 50000, E = 800000, G = 128, H = 256, F = 128;
    const int NPAD = 50048;            // 391 * 128
    const int NB = (N + 255) / 256;    // 196

    // workspace; region0 reused: {xh, S1}
    char* p = (char*)d_ws;
    char* region0 = p;                  p += (size_t)N * H * sizeof(float);    // 51.2 MB
    ushort* xh = (ushort*)region0;                                             // [N,128] bf16
    ushort* S1 = (ushort*)(region0 + (size_t)N * F * sizeof(ushort));          // [NPAD,128] bf16
    ushort* h1 = (ushort*)p;            p += (size_t)N * H * sizeof(ushort);   // [N,256] bf16
    ushort* S2 = (ushort*)p;            p += (size_t)NPAD * H * sizeof(ushort);// [NPAD,256] bf16
    float* g   = (float*)p;             p += (size_t)G * H * sizeof(float);
    int*   deg = (int*)p;               p += (size_t)N * sizeof(int);
    int*   off = (int*)p;               p += (size_t)(N + 1) * sizeof(int) + 12;
    int*   cur = (int*)p;               p += (size_t)N * sizeof(int);
    int*   bsum= (int*)p;               p += 256 * sizeof(int);
    uint2* edges=(uint2*)p;             p += (size_t)E * sizeof(uint2);        // packed (src,w)
    ushort* Wt1= (ushort*)p;            p += (size_t)H * F * sizeof(ushort);   // [256,128]
    ushort* Wt2= (ushort*)p;            p += (size_t)H * H * sizeof(ushort);   // [256,256]

    // ---- prep (x->bf16, deg hist, W^T) + CSR build (csr_fill also zeroes g) ----
    hipMemsetAsync(deg, 0, (size_t)N * sizeof(int), stream);
    prep<<<9887, 256, 0, stream>>>(x, xh, edst, deg, W1, Wt1, W2, Wt2, E);
    scan_block<<<NB, 256, 0, stream>>>(deg, off, bsum, N);
    scan_apply<<<NB, 256, 0, stream>>>(off, bsum, cur, N, E, NB);
    csr_fill<<<(E + 255) / 256, 256, 0, stream>>>(esrc, edst, ew, cur, edges, g, E);

    // ---- layer 1: S1 = A@x ; h1 = relu(S1@W1 + b1) ----
    spmm128<<<(N + 3) / 4, 256, 0, stream>>>(xh, off, edges, S1, N);
    gemm_tile<128, true, false><<<dim3(NPAD / 128, 2), 256, 0, stream>>>(
        S1, Wt1, b1, h1, nullptr, nullptr, N);

    // ---- layer 2: S2 = A@h1 ; pool(relu(S2@W2+b2)) fused into epilogue ----
    spmm256<<<(N + 3) / 4, 256, 0, stream>>>(h1, off, edges, S2, N);
    gemm_tile<256, false, true><<<dim3(NPAD / 128, 2), 256, 0, stream>>>(
        S2, Wt2, b2, nullptr, seg, g, N);

    // ---- head ----
    head<<<G, 256, 0, stream>>>(g, Wd, bd, Wo, bo, out);
}